// Round 1
// baseline (164.473 us; speedup 1.0000x reference)
//
#include <hip/hip_runtime.h>
#include <hip/hip_bf16.h>

typedef unsigned short u16;
typedef __attribute__((ext_vector_type(8))) short bf16x8;
typedef __attribute__((ext_vector_type(4))) float f32x4;

#define NB 16
#define NN 2048
#define FF 256
#define LOG2E 1.4426950408889634f

__device__ __forceinline__ u16 f2bf(float x) {
    union { float f; unsigned u; } v; v.f = x;
    unsigned r = v.u + 0x7fffu + ((v.u >> 16) & 1u);
    return (u16)(r >> 16);
}

#define GLD_LDS(g, l) __builtin_amdgcn_global_load_lds((const __attribute__((address_space(1))) void*)(g), (__attribute__((address_space(3))) void*)(l), 16, 0, 0)

// ---------------- Kernel A: u1 = W@a1, u2 = W@a2 (fp32), WT = W^T in bf16 ----------------
__global__ __launch_bounds__(256) void k_prep_w(const float* __restrict__ W, const float* __restrict__ a,
                                                u16* __restrict__ WT, float* __restrict__ u1, float* __restrict__ u2) {
    int b = blockIdx.y, t = threadIdx.x;
    __shared__ float a1s[FF], a2s[FF];
    a1s[t] = a[b*2*FF + t];
    a2s[t] = a[b*2*FF + FF + t];
    __syncthreads();
    int f = blockIdx.x*64 + (t >> 2);
    int o0 = (t & 3) * 64;
    const float* wrow = W + (size_t)(b*FF + f)*FF + o0;
    u16* wtb = WT + (size_t)b*FF*FF;
    float s1 = 0.f, s2 = 0.f;
#pragma unroll
    for (int c = 0; c < 16; ++c) {
        float4 v = *(const float4*)(wrow + c*4);
        int o = o0 + c*4;
        s1 += v.x*a1s[o] + v.y*a1s[o+1] + v.z*a1s[o+2] + v.w*a1s[o+3];
        s2 += v.x*a2s[o] + v.y*a2s[o+1] + v.z*a2s[o+2] + v.w*a2s[o+3];
        wtb[(size_t)(o+0)*FF + f] = f2bf(v.x);
        wtb[(size_t)(o+1)*FF + f] = f2bf(v.y);
        wtb[(size_t)(o+2)*FF + f] = f2bf(v.z);
        wtb[(size_t)(o+3)*FF + f] = f2bf(v.w);
    }
    s1 += __shfl_xor(s1, 1); s1 += __shfl_xor(s1, 2);
    s2 += __shfl_xor(s2, 1); s2 += __shfl_xor(s2, 2);
    if ((t & 3) == 0) { u1[b*FF + f] = s1; u2[b*FF + f] = s2; }
}

// ---------------- Kernel B: Wh1 = h@u1, Wh2 = h@u2 (fp32 exact), h_bf16 copy ----------------
__global__ __launch_bounds__(256) void k_prep_h(const float* __restrict__ h, const float* __restrict__ u1,
                                                const float* __restrict__ u2, u16* __restrict__ hbf,
                                                float* __restrict__ Wh1, float* __restrict__ Wh2) {
    int b = blockIdx.y, t = threadIdx.x;
    __shared__ float u1s[FF], u2s[FF];
    u1s[t] = u1[b*FF + t];
    u2s[t] = u2[b*FF + t];
    __syncthreads();
    int wave = t >> 6, lane = t & 63;
    int i = blockIdx.x*4 + wave;
    size_t rowoff = ((size_t)(b*NN + i))*FF + lane*4;
    float4 v = *(const float4*)(h + rowoff);
    u16 h0 = f2bf(v.x), h1 = f2bf(v.y), h2 = f2bf(v.z), h3 = f2bf(v.w);
    unsigned p0 = (unsigned)h0 | ((unsigned)h1 << 16);
    unsigned p1 = (unsigned)h2 | ((unsigned)h3 << 16);
    uint2 pk; pk.x = p0; pk.y = p1;
    *(uint2*)(hbf + rowoff) = pk;
    int o = lane*4;
    float s1 = v.x*u1s[o] + v.y*u1s[o+1] + v.z*u1s[o+2] + v.w*u1s[o+3];
    float s2 = v.x*u2s[o] + v.y*u2s[o+1] + v.z*u2s[o+2] + v.w*u2s[o+3];
#pragma unroll
    for (int off = 32; off > 0; off >>= 1) { s1 += __shfl_xor(s1, off); s2 += __shfl_xor(s2, off); }
    if (lane == 0) { Wh1[b*NN + i] = s1; Wh2[b*NN + i] = s2; }
}

// ---------------- Kernel C: WhT[b][o][i] = bf16( (h@W)^T )  via MFMA ----------------
// D[m=o][n=i] = sum_f WT[o][f] * hbf[i][f]
__global__ __launch_bounds__(256) void k_gemm1(const u16* __restrict__ WT, const u16* __restrict__ hbf,
                                               u16* __restrict__ WhT) {
    int b = blockIdx.z;
    int o0 = blockIdx.y * 64;
    int i0 = blockIdx.x * 256;
    int t = threadIdx.x, lane = t & 63, w = t >> 6;
    __shared__ alignas(16) u16 At[64*64];
    __shared__ alignas(16) u16 Btl[256*64];
    const u16* WTb = WT + (size_t)b*FF*FF;
    const u16* hb  = hbf + (size_t)b*NN*FF;

    f32x4 acc[4][4];
#pragma unroll
    for (int x = 0; x < 4; ++x)
#pragma unroll
        for (int y = 0; y < 4; ++y) acc[x][y] = (f32x4)0.f;

    for (int kk = 0; kk < 4; ++kk) {
        int k0 = kk*64;
#pragma unroll
        for (int is = 0; is < 2; ++is) {
            int s = is*256 + t;
            int row = s >> 3, jbp = s & 7;
            int jbl = jbp ^ (row & 7);
            GLD_LDS(WTb + (size_t)(o0+row)*FF + k0 + jbl*8, &At[s*8]);
        }
#pragma unroll
        for (int is = 0; is < 8; ++is) {
            int s = is*256 + t;
            int row = s >> 3, jbp = s & 7;
            int jbl = jbp ^ (row & 7);
            GLD_LDS(hb + (size_t)(i0+row)*FF + k0 + jbl*8, &Btl[s*8]);
        }
        __syncthreads();
#pragma unroll
        for (int kc = 0; kc < 2; ++kc) {
            int jl = kc*4 + (lane >> 4);
            bf16x8 af[4], bfr[4];
#pragma unroll
            for (int mi = 0; mi < 4; ++mi) {
                int r = mi*16 + (lane & 15);
                af[mi] = *(const bf16x8*)&At[r*64 + (jl ^ (r & 7))*8];
            }
#pragma unroll
            for (int ni = 0; ni < 4; ++ni) {
                int r = w*64 + ni*16 + (lane & 15);
                bfr[ni] = *(const bf16x8*)&Btl[r*64 + (jl ^ (r & 7))*8];
            }
#pragma unroll
            for (int mi = 0; mi < 4; ++mi)
#pragma unroll
                for (int ni = 0; ni < 4; ++ni)
                    acc[mi][ni] = __builtin_amdgcn_mfma_f32_16x16x32_bf16(af[mi], bfr[ni], acc[mi][ni], 0, 0, 0);
        }
        __syncthreads();
    }
    u16* Wo = WhT + (size_t)b*FF*NN;
#pragma unroll
    for (int mi = 0; mi < 4; ++mi)
#pragma unroll
        for (int ni = 0; ni < 4; ++ni) {
            int i = i0 + w*64 + ni*16 + (lane & 15);
#pragma unroll
            for (int rr = 0; rr < 4; ++rr) {
                int o = o0 + mi*16 + (lane >> 4)*4 + rr;
                Wo[(size_t)o*NN + i] = f2bf(acc[mi][ni][rr]);
            }
        }
}

// ---------------- Kernel D: column exp-sums (axis=1 softmax denom) + adj bit-pack ----------------
__global__ __launch_bounds__(256) void k_colsum(const int* __restrict__ adj, const float* __restrict__ Wh1,
                                                const float* __restrict__ Wh2, float* __restrict__ pS,
                                                unsigned long long* __restrict__ packed) {
    int b = blockIdx.z, ic = blockIdx.y, jt = blockIdx.x;
    int t = threadIdx.x, lane = t & 63, wave = t >> 6;
    __shared__ float wh1s[256];
    int ibase = ic*256;
    wh1s[t] = Wh1[b*NN + ibase + t];
    __syncthreads();
    int j = jt*256 + t;
    float wh2j = Wh2[b*NN + j];
    const int* acol = adj + (size_t)b*NN*NN + (size_t)ibase*NN + j;
    unsigned long long* prow = packed + ((size_t)(b*NN + ibase))*32 + jt*4 + wave;
    float s = 0.f;
    for (int ii = 0; ii < 256; ii += 8) {
        int v[8];
#pragma unroll
        for (int r = 0; r < 8; ++r) v[r] = acol[(size_t)(ii + r)*NN];
#pragma unroll
        for (int r = 0; r < 8; ++r) {
            bool p = v[r] > 0;
            unsigned long long m = __ballot(p);
            if (lane == 0) prow[(size_t)(ii + r)*32] = m;
            float tt = wh1s[ii + r] + wh2j;
            float lr = fmaxf(tt, 0.2f*tt);
            float e = __expf(lr);
            s += p ? e : 0.f;
        }
    }
    pS[((size_t)(b*8 + ic))*NN + j] = s;
}

// ---------------- Kernel E: combine partial sums -> log2(S) ----------------
__global__ __launch_bounds__(256) void k_combine(const float* __restrict__ pS, float* __restrict__ lns2) {
    int idx = blockIdx.x*256 + threadIdx.x;   // b*2048 + j
    int b = idx >> 11, j = idx & 2047;
    float s = 0.f;
#pragma unroll
    for (int c = 0; c < 8; ++c) s += pS[((size_t)(b*8 + c))*NN + j];
    lns2[idx] = (s > 0.f) ? log2f(s) : __builtin_inff();
}

// ---------------- Kernel F: out = elu( att @ Wh ), att generated on the fly ----------------
// D[m=i][n=o] = sum_j att[i][j] * WhT[o][j]
__global__ __launch_bounds__(512) void k_gemm3(const u16* __restrict__ WhT, const unsigned long long* __restrict__ packed,
                                               const float* __restrict__ Wh1, const float* __restrict__ Wh2,
                                               const float* __restrict__ lns2, float* __restrict__ out) {
    int b = blockIdx.y;
    int i0 = blockIdx.x * 128;
    int t = threadIdx.x, lane = t & 63, wave = t >> 6;
    int wm = wave >> 2, wn = wave & 3;
    __shared__ alignas(16) u16 At[2][128*64];
    __shared__ alignas(16) u16 Bt[2][256*64];
    __shared__ float wh2s[NN];
    __shared__ float lss[NN];
    __shared__ float wh1s[128];

#pragma unroll
    for (int c = 0; c < 4; ++c) {
        int idx = c*512 + t;
        wh2s[idx] = Wh2[b*NN + idx];
        lss[idx]  = lns2[b*NN + idx];
    }
    if (t < 128) wh1s[t] = Wh1[b*NN + i0 + t];

    const u16* Wo = WhT + (size_t)b*FF*NN;
    const u16* pk = (const u16*)(packed + ((size_t)b*NN)*32);
    int rA = t >> 2, qA = t & 3;

    __syncthreads();  // tables ready

    f32x4 acc[4][4];
#pragma unroll
    for (int x = 0; x < 4; ++x)
#pragma unroll
        for (int y = 0; y < 4; ++y) acc[x][y] = (f32x4)0.f;

    auto stageB = [&](int kk, int bbuf) {
        int k0 = kk*64;
#pragma unroll
        for (int is = 0; is < 4; ++is) {
            int s = is*512 + t;
            int row = s >> 3, jbp = s & 7;
            int jbl = jbp ^ (row & 7);
            GLD_LDS(Wo + (size_t)row*NN + k0 + jbl*8, &Bt[bbuf][s*8]);
        }
    };
    auto genA = [&](int kk, int bbuf) {
        unsigned mask = pk[(size_t)(i0 + rA)*128 + kk*4 + qA];
        float wh1r = wh1s[rA];
        int jb = kk*64 + qA*16;
        const float4* w2p = (const float4*)&wh2s[jb];
        const float4* lsp = (const float4*)&lss[jb];
        union { u16 u[16]; bf16x8 v[2]; } ob;
#pragma unroll
        for (int c = 0; c < 4; ++c) {
            float4 w2 = w2p[c];
            float4 ls = lsp[c];
            float xs[4] = {w2.x, w2.y, w2.z, w2.w};
            float lv[4] = {ls.x, ls.y, ls.z, ls.w};
#pragma unroll
            for (int e = 0; e < 4; ++e) {
                float tt = wh1r + xs[e];
                float lr = fmaxf(tt, 0.2f*tt);
                float pe = exp2f(lr*LOG2E - lv[e]);
                int bit = (mask >> (c*4 + e)) & 1;
                ob.u[c*4 + e] = bit ? f2bf(pe) : (u16)0;
            }
        }
        int rx = rA & 7;
#pragma unroll
        for (int c2 = 0; c2 < 2; ++c2)
            *(bf16x8*)&At[bbuf][rA*64 + ((qA*2 + c2) ^ rx)*8] = ob.v[c2];
    };

    int bb = 0;
    stageB(0, 0);
    genA(0, 0);
    __syncthreads();

    for (int kk = 0; kk < 32; ++kk) {
        int nb = bb ^ 1;
        if (kk + 1 < 32) { stageB(kk+1, nb); genA(kk+1, nb); }
#pragma unroll
        for (int kc = 0; kc < 2; ++kc) {
            int jl = kc*4 + (lane >> 4);
            bf16x8 af[4], bfr[4];
#pragma unroll
            for (int mi = 0; mi < 4; ++mi) {
                int r = wm*64 + mi*16 + (lane & 15);
                af[mi] = *(const bf16x8*)&At[bb][r*64 + (jl ^ (r & 7))*8];
            }
#pragma unroll
            for (int ni = 0; ni < 4; ++ni) {
                int r = wn*64 + ni*16 + (lane & 15);
                bfr[ni] = *(const bf16x8*)&Bt[bb][r*64 + (jl ^ (r & 7))*8];
            }
#pragma unroll
            for (int mi = 0; mi < 4; ++mi)
#pragma unroll
                for (int ni = 0; ni < 4; ++ni)
                    acc[mi][ni] = __builtin_amdgcn_mfma_f32_16x16x32_bf16(af[mi], bfr[ni], acc[mi][ni], 0, 0, 0);
        }
        __syncthreads();
        bb = nb;
    }

    float* ob2 = out + ((size_t)b*NN)*FF;
#pragma unroll
    for (int mi = 0; mi < 4; ++mi)
#pragma unroll
        for (int ni = 0; ni < 4; ++ni) {
            int o = wn*64 + ni*16 + (lane & 15);
#pragma unroll
            for (int rr = 0; rr < 4; ++rr) {
                int i = i0 + wm*64 + mi*16 + (lane >> 4)*4 + rr;
                float x = acc[mi][ni][rr];
                float y = (x > 0.f) ? x : (exp2f(x*LOG2E) - 1.f);
                ob2[(size_t)i*FF + o] = y;
            }
        }
}

extern "C" void kernel_launch(void* const* d_in, const int* in_sizes, int n_in,
                              void* d_out, int out_size, void* d_ws, size_t ws_size,
                              hipStream_t stream) {
    const float* h   = (const float*)d_in[0];
    const int*   adj = (const int*)d_in[1];
    const float* W   = (const float*)d_in[2];
    const float* a   = (const float*)d_in[3];
    float* out = (float*)d_out;

    char* w = (char*)d_ws;
    const size_t MB = 1u << 20;
    u16* WT  = (u16*)(w + 0);            //  2 MB  [16][256][256]  W^T bf16 (o-major, f-contig)
    u16* hbf = (u16*)(w + 2*MB);         // 16 MB  [16][2048][256] h bf16
    u16* WhT = (u16*)(w + 18*MB);        // 16 MB  [16][256][2048] Wh^T bf16 (o-major, j-contig)
    unsigned long long* packed = (unsigned long long*)(w + 34*MB);  // 8 MB [16][2048][32] adj bitmask
    float* pS  = (float*)(w + 42*MB);    //  1 MB  [16][8][2048] partial col sums
    float* Wh1 = (float*)(w + 43*MB);                   // 128 KB
    float* Wh2 = (float*)(w + 43*MB + 131072);          // 128 KB
    float* lns = (float*)(w + 43*MB + 2*131072);        // 128 KB
    float* u1  = (float*)(w + 43*MB + 3*131072);        //  16 KB
    float* u2  = (float*)(w + 43*MB + 3*131072 + 16384);

    k_prep_w<<<dim3(4, 16), 256, 0, stream>>>(W, a, WT, u1, u2);
    k_prep_h<<<dim3(512, 16), 256, 0, stream>>>(h, u1, u2, hbf, Wh1, Wh2);
    k_gemm1<<<dim3(8, 4, 16), 256, 0, stream>>>(WT, hbf, WhT);
    k_colsum<<<dim3(8, 8, 16), 256, 0, stream>>>(adj, Wh1, Wh2, pS, packed);
    k_combine<<<128, 256, 0, stream>>>(pS, lns);
    k_gemm3<<<dim3(16, 16), 512, 0, stream>>>(WhT, packed, Wh1, Wh2, lns, out);
}